// Round 4
// baseline (1017.991 us; speedup 1.0000x reference)
//
#include <hip/hip_runtime.h>
#include <math.h>

#define B_  128
#define T_  2048
#define D_  128
#define M_  64
#define BT_ (B_*T_)
#define TC_ 64              // scan chunk timesteps
#define NC_ (T_/TC_)        // 32 chunks

// async global->LDS, 16B per lane. Dest must be wave-uniform base + lane*16.
#define GLL16(src, dst)                                                     \
  __builtin_amdgcn_global_load_lds(                                         \
      (const __attribute__((address_space(1))) void*)(src),                 \
      (__attribute__((address_space(3))) void*)(dst), 16, 0, 0)

// DPP reduce over 8 contiguous lanes (half-row): xor1, xor2, then half-mirror.
__device__ __forceinline__ float dpp_add8(float x) {
  int v;
  v = __builtin_amdgcn_update_dpp(0, __float_as_int(x), 0xB1, 0xf, 0xf, true);
  x += __int_as_float(v);   // quad_perm [1,0,3,2]  (xor 1)
  v = __builtin_amdgcn_update_dpp(0, __float_as_int(x), 0x4E, 0xf, 0xf, true);
  x += __int_as_float(v);   // quad_perm [2,3,0,1]  (xor 2)
  v = __builtin_amdgcn_update_dpp(0, __float_as_int(x), 0x141, 0xf, 0xf, true);
  x += __int_as_float(v);   // row_half_mirror      (xor 4 after the above)
  return x;
}
__device__ __forceinline__ float dpp_max8(float x) {
  int v;
  v = __builtin_amdgcn_update_dpp(0, __float_as_int(x), 0xB1, 0xf, 0xf, true);
  x = fmaxf(x, __int_as_float(v));
  v = __builtin_amdgcn_update_dpp(0, __float_as_int(x), 0x4E, 0xf, 0xf, true);
  x = fmaxf(x, __int_as_float(v));
  v = __builtin_amdgcn_update_dpp(0, __float_as_int(x), 0x141, 0xf, 0xf, true);
  x = fmaxf(x, __int_as_float(v));
  return x;
}

// ---------------------------------------------------------------------------
// K0: build Wt[k][320]  (transposed, concatenated weights)
//   n in [0,128) -> e_w[n][k]; [128,256) -> a_w; [256,320) -> MS
// ---------------------------------------------------------------------------
__global__ void k_transpose(const float* __restrict__ e_w,
                            const float* __restrict__ a_w,
                            const float* __restrict__ MS,
                            float* __restrict__ Wt) {
  int k = blockIdx.x;
  int n = threadIdx.x;
  float v;
  if (n < 128)      v = e_w[n * D_ + k];
  else if (n < 256) v = a_w[(n - 128) * D_ + k];
  else              v = MS[(n - 256) * D_ + k];
  Wt[k * 320 + n] = v;
}

// ---------------------------------------------------------------------------
// K1: fused GEMM  [BT,128] x Wt[128,320] -> {e, a, w(softmax)}
// 128-thr blocks (2 waves), tile 128 rows x 64 cols, thread tile 8x8.
// 2 blocks/CU (64KB LDS) = 4 waves/CU -> DS issue < VALU: VALU-bound.
// X LDS k-blocks rotated by (row>>3) at the global source (G21: swizzle
// source + read, LDS dest linear) to break row-stride bank conflicts.
// Block remap groups the 5 col-blocks of a row-slice onto one XCD (L2 reuse).
// ---------------------------------------------------------------------------
__global__ __launch_bounds__(128, 1)
void k_gemm(const float* __restrict__ q, const float* __restrict__ qa,
            const float* __restrict__ Wt, const float* __restrict__ e_b,
            const float* __restrict__ a_b, float* __restrict__ w_ws,
            float* __restrict__ e_ws, float* __restrict__ a_ws) {
  __shared__ float Wl[128 * 64];      // 32KB [k][64]
  __shared__ float Xl[2][128 * 32];   // 2x16KB [row][32k], k-blocks rotated

  // XCD-grouping remap: 10240 blocks = 8 xcd * 1280; within an XCD iterate
  // (y_local, x) with x fastest -> same-row col-blocks share the XCD L2.
  const int bid  = blockIdx.x;
  const int xcd  = bid & 7;
  const int i    = bid >> 3;            // 0..1279
  const int nb   = i % 5;               // col-block 0..4
  const int rb   = xcd * 256 + i / 5;   // row-block 0..2047
  const int tid  = threadIdx.x;
  const int tx   = tid & 7;
  const int ty   = tid >> 3;            // 0..15
  const int r0   = rb * 128;
  const int n0   = nb * 64;
  const float* X = (nb == 4) ? q : qa;

  // stage whole W tile: 8192 floats = 2048 16B-units, 16/thread
#pragma unroll
  for (int u16 = 0; u16 < 16; ++u16) {
    int u = tid + u16 * 128;
    int k = u >> 4, col = (u & 15) * 4;
    GLL16(Wt + (size_t)k * 320 + n0 + col, Wl + u * 4);
  }

  auto STAGEX = [&](int buf, int k0) {
#pragma unroll
    for (int u8 = 0; u8 < 8; ++u8) {
      int u   = tid + u8 * 128;          // 1024 units
      int row = u >> 3;
      int kb  = u & 7;
      int kbs = (kb + (row >> 3)) & 7;   // source k-block rotation
      GLL16(X + (size_t)(r0 + row) * 128 + k0 + kbs * 4, Xl[buf] + u * 4);
    }
  };

  float acc[8][8];
#pragma unroll
  for (int a = 0; a < 8; ++a)
#pragma unroll
    for (int b = 0; b < 8; ++b) acc[a][b] = 0.f;

  STAGEX(0, 0);
  __syncthreads();                      // drains W + X chunk 0

  const int rot = ty & 7;
  for (int c = 0; c < 4; ++c) {
    if (c < 3) STAGEX((c + 1) & 1, (c + 1) * 32);
    const float* Xb = Xl[c & 1];
    const float* Wb = Wl + c * 32 * 64;
#pragma unroll
    for (int k4 = 0; k4 < 8; ++k4) {
      const int ldsb = (k4 - rot) & 7;
      float4 xv[8];
#pragma unroll
      for (int r = 0; r < 8; ++r)
        xv[r] = *(const float4*)(Xb + (size_t)(ty * 8 + r) * 32 + ldsb * 4);
      float4 wv0[4], wv1[4];
#pragma unroll
      for (int kk = 0; kk < 4; ++kk) {
        wv0[kk] = *(const float4*)(Wb + (size_t)(k4 * 4 + kk) * 64 + tx * 8);
        wv1[kk] = *(const float4*)(Wb + (size_t)(k4 * 4 + kk) * 64 + tx * 8 + 4);
      }
#pragma unroll
      for (int kk = 0; kk < 4; ++kk) {
#pragma unroll
        for (int r = 0; r < 8; ++r) {
          float xk = ((const float*)&xv[r])[kk];
          acc[r][0] = fmaf(xk, wv0[kk].x, acc[r][0]);
          acc[r][1] = fmaf(xk, wv0[kk].y, acc[r][1]);
          acc[r][2] = fmaf(xk, wv0[kk].z, acc[r][2]);
          acc[r][3] = fmaf(xk, wv0[kk].w, acc[r][3]);
          acc[r][4] = fmaf(xk, wv1[kk].x, acc[r][4]);
          acc[r][5] = fmaf(xk, wv1[kk].y, acc[r][5]);
          acc[r][6] = fmaf(xk, wv1[kk].z, acc[r][6]);
          acc[r][7] = fmaf(xk, wv1[kk].w, acc[r][7]);
        }
      }
    }
    __syncthreads();
  }

  if (nb == 4) {
    // softmax over 64 cols; row's 8 threads = one 8-lane half-row -> DPP
#pragma unroll
    for (int r = 0; r < 8; ++r) {
      float mx = acc[r][0];
#pragma unroll
      for (int j = 1; j < 8; ++j) mx = fmaxf(mx, acc[r][j]);
      mx = dpp_max8(mx);
      float ex[8]; float sum = 0.f;
#pragma unroll
      for (int j = 0; j < 8; ++j) { ex[j] = expf(acc[r][j] - mx); sum += ex[j]; }
      sum = dpp_add8(sum);
      float inv = 1.0f / sum;
      float* dst = w_ws + (size_t)(r0 + ty * 8 + r) * M_ + tx * 8;
      *(float4*)(dst)     = make_float4(ex[0]*inv, ex[1]*inv, ex[2]*inv, ex[3]*inv);
      *(float4*)(dst + 4) = make_float4(ex[4]*inv, ex[5]*inv, ex[6]*inv, ex[7]*inv);
    }
  } else {
    const int n = n0 + tx * 8;            // 0..255, block-uniform e-vs-a
    const bool is_e = (n < 128);
    const float* bias = is_e ? (e_b + n) : (a_b + (n - 128));
    float bb[8];
#pragma unroll
    for (int j = 0; j < 8; ++j) bb[j] = bias[j];
    float* dst0 = is_e ? e_ws : a_ws;
    const int cn = n & 127;
#pragma unroll
    for (int r = 0; r < 8; ++r) {
      float o[8];
      if (is_e) {
#pragma unroll
        for (int j = 0; j < 8; ++j)
          o[j] = 1.f / (1.f + expf(-(acc[r][j] + bb[j])));
      } else {
#pragma unroll
        for (int j = 0; j < 8; ++j)
          o[j] = tanhf(acc[r][j] + bb[j]);
      }
      float* dst = dst0 + (size_t)(r0 + ty * 8 + r) * D_ + cn;
      *(float4*)(dst)     = make_float4(o[0], o[1], o[2], o[3]);
      *(float4*)(dst + 4) = make_float4(o[4], o[5], o[6], o[7]);
    }
  }
}

// ---------------------------------------------------------------------------
// K2: sequential scan. 256 blocks = (b, d-half of 64), 1 block/CU, 4 waves.
// Thread = 8 m x 2 d: mem[8][2] in regs. Per step DS = 2 b128 (w) +
// 2 b64 (e,a); m-reduce on VALU via DPP (no DS). w/e/a LDS-chunked (TC=64,
// 48KB x 2 buffers) via bulk global_load_lds, prefetched a chunk ahead.
// ---------------------------------------------------------------------------
__global__ __launch_bounds__(256, 1)
void k_scan(const float* __restrict__ w_ws, const float* __restrict__ e_ws,
            const float* __restrict__ a_ws, const float* __restrict__ dy,
            float* __restrict__ out) {
  // per chunk: w TC*64 | e TC*64 | a TC*64 floats = 48KB
  __shared__ float lds[2][TC_ * 192];

  // bijective XCD swizzle of 256 = 8*32; (b,h) pairs stay on one XCD.
  int o = ((blockIdx.x & 7) << 5) | (blockIdx.x >> 3);
  int b = o >> 1;
  int h = o & 1;                        // d-half

  const int tid  = threadIdx.x;
  const int lane = tid & 63;
  const int wv   = tid >> 6;
  const int mg   = lane & 7;            // m-octet id (8-lane half-row)
  const int dl8  = lane >> 3;           // 0..7
  const int m0   = mg << 3;
  const int dloc = (wv << 4) + (dl8 << 1);   // 0..62 even
  const int d    = (h << 6) + dloc;

  float mem[8][2];
#pragma unroll
  for (int j = 0; j < 8; ++j) {
    mem[j][0] = dy[(size_t)(m0 + j) * D_ + d];
    mem[j][1] = dy[(size_t)(m0 + j) * D_ + d + 1];
  }

  const float* wbase = w_ws + (size_t)b * T_ * M_;
  const float* ebase = e_ws + (size_t)b * T_ * D_ + (h << 6);
  const float* abase = a_ws + (size_t)b * T_ * D_ + (h << 6);
  float*       op    = out  + (size_t)b * T_ * D_ + d;

  auto STAGE = [&](int buf, int c) {
    const int t0 = c * TC_;
    float* L = lds[buf];
    // w: TC*64 contiguous floats -> 1024 units, 4/thread
#pragma unroll
    for (int u4 = 0; u4 < 4; ++u4) {
      int u = tid + u4 * 256;
      GLL16(wbase + (size_t)t0 * 64 + u * 4, L + u * 4);
    }
    // e: TC rows of 64 floats (16 units/row) -> 1024 units
#pragma unroll
    for (int u4 = 0; u4 < 4; ++u4) {
      int u = tid + u4 * 256;
      int t = u >> 4, inner = (u & 15) * 4;
      GLL16(ebase + (size_t)(t0 + t) * D_ + inner, L + TC_ * 64 + u * 4);
    }
    // a: same
#pragma unroll
    for (int u4 = 0; u4 < 4; ++u4) {
      int u = tid + u4 * 256;
      int t = u >> 4, inner = (u & 15) * 4;
      GLL16(abase + (size_t)(t0 + t) * D_ + inner, L + TC_ * 128 + u * 4);
    }
  };

  STAGE(0, 0);
  __syncthreads();

  for (int c = 0; c < NC_; ++c) {
    if (c + 1 < NC_) STAGE((c + 1) & 1, c + 1);
    const float* Lw = lds[c & 1];
    const float* Le = Lw + TC_ * 64;
    const float* La = Lw + TC_ * 128;
    const int t0 = c * TC_;

    // 1-step register prefetch pipeline
    float4 nw0 = *(const float4*)(Lw + m0);
    float4 nw1 = *(const float4*)(Lw + m0 + 4);
    float2 ne  = *(const float2*)(Le + dloc);
    float2 na  = *(const float2*)(La + dloc);

#pragma unroll 4
    for (int tt = 0; tt < TC_; ++tt) {
      float4 w0 = nw0, w1 = nw1;
      float2 ev = ne, av = na;
      int tn = (tt + 1 < TC_) ? tt + 1 : TC_ - 1;
      nw0 = *(const float4*)(Lw + tn * 64 + m0);
      nw1 = *(const float4*)(Lw + tn * 64 + m0 + 4);
      ne  = *(const float2*)(Le + tn * 64 + dloc);
      na  = *(const float2*)(La + tn * 64 + dloc);

      float wv8[8] = {w0.x, w0.y, w0.z, w0.w, w1.x, w1.y, w1.z, w1.w};
      float r0 = 0.f, r1 = 0.f;
#pragma unroll
      for (int j = 0; j < 8; ++j) {
        r0 = fmaf(wv8[j], mem[j][0], r0);
        r1 = fmaf(wv8[j], mem[j][1], r1);
        float h0 = fmaf(-ev.x, mem[j][0], av.x);   // a - e*mem
        float h1 = fmaf(-ev.y, mem[j][1], av.y);
        mem[j][0] = fmaf(wv8[j], h0, mem[j][0]);   // mem += w*h
        mem[j][1] = fmaf(wv8[j], h1, mem[j][1]);
      }
      r0 = dpp_add8(r0);
      r1 = dpp_add8(r1);
      if (mg == 0)
        *(float2*)(op + (size_t)(t0 + tt) * D_) = make_float2(r0, r1);
    }
    __syncthreads();
  }
}

// ---------------------------------------------------------------------------
extern "C" void kernel_launch(void* const* d_in, const int* in_sizes, int n_in,
                              void* d_out, int out_size, void* d_ws, size_t ws_size,
                              hipStream_t stream) {
  const float* q      = (const float*)d_in[0];
  const float* qa     = (const float*)d_in[1];
  const float* MS     = (const float*)d_in[2];
  const float* dy_mem = (const float*)d_in[3];
  const float* e_w    = (const float*)d_in[4];
  const float* e_b    = (const float*)d_in[5];
  const float* a_w    = (const float*)d_in[6];
  const float* a_b    = (const float*)d_in[7];
  float* out = (float*)d_out;

  float* Wt  = (float*)d_ws;                       // 128*320
  float* wws = Wt  + (size_t)128 * 320;            // BT*64
  float* ews = wws + (size_t)BT_ * M_;             // BT*128
  float* aws = ews + (size_t)BT_ * D_;             // BT*128

  k_transpose<<<128, 320, 0, stream>>>(e_w, a_w, MS, Wt);
  k_gemm<<<10240, 128, 0, stream>>>(q, qa, Wt, e_b, a_b, wws, ews, aws);
  k_scan<<<256, 256, 0, stream>>>(wws, ews, aws, dy_mem, out);
}